// Round 6
// baseline (270.999 us; speedup 1.0000x reference)
//
#include <hip/hip_runtime.h>
#include <hip/hip_fp16.h>
#include <cfloat>
#include <cmath>

#define DIM 64
#define HEADS 4
#define NEG 0.2f
#define CAP 64          // bucket capacity; deg ~ Poisson(16), P(any node >64) ~ 1e-13
#define NPART 8         // dst partitions == XCD count; blockIdx&7 -> XCD (round-robin)
#define BPP 96          // fill blocks per partition

typedef int v4i __attribute__((ext_vector_type(4)));

__device__ __forceinline__ float lrelu(float a) { return a > 0.0f ? a : NEG * a; }

__device__ __forceinline__ unsigned pack_half2(float a, float b) {
    return (unsigned)__half_as_ushort(__float2half(a)) |
           ((unsigned)__half_as_ushort(__float2half(b)) << 16);
}

// ==================== K1: prep ====================
// b<64   : M2h[(h*64+d)][j] = fp16( sum_c W[d][64h+c]*dw[64h+c][j] )   (d = blockIdx)
// b==64  : bvec[j] = sum_k bias[k]*dw[k][j] + db[j]
// b>=65  : 64-node tile: logits a_src/a_dst = e.(W*att); emb16 row pack; zero cnt.
__global__ __launch_bounds__(256) void prep_kernel(
        const float* __restrict__ W, const float* __restrict__ dw,
        const float* __restrict__ att_s, const float* __restrict__ att_d,
        const float* __restrict__ bias, const float* __restrict__ db,
        const float* __restrict__ emb,
        __half* __restrict__ M2h, float* __restrict__ bvec,
        float* __restrict__ a_src, float* __restrict__ a_dst,
        unsigned* __restrict__ embh, int* __restrict__ cnt, int N) {
    const int b = blockIdx.x, t = threadIdx.x;
    if (b < 64) {
        __shared__ float s_W[256];
        s_W[t] = W[b * 256 + t];
        __syncthreads();
        const int h = t >> 6, j = t & 63;
        float s = 0.f;
        for (int c = 0; c < 64; c++)
            s = fmaf(s_W[h * 64 + c], dw[(h * 64 + c) * 64 + j], s);
        M2h[(size_t)(h * 64 + b) * 64 + j] = __float2half(s);
    } else if (b == 64) {
        __shared__ float s_p[256];
        const int j = t & 63, kq = t >> 6;
        float p = 0.f;
        for (int k = kq * 64; k < kq * 64 + 64; k++)
            p = fmaf(bias[k], dw[k * 64 + j], p);
        s_p[t] = p;
        __syncthreads();
        if (t < 64)
            bvec[t] = s_p[t] + s_p[64 + t] + s_p[128 + t] + s_p[192 + t] + db[t];
    } else {
        __shared__ float s_e[64 * 68];      // 64 emb rows, pad 68
        __shared__ float s_vs[256], s_vd[256];  // layout [h][d] = h*64+d
        const int n0 = (b - 65) * 64;
        // va: thread t -> (d = t>>2, h = t&3); vectorized float4 dots
        {
            const int d = t >> 2, h = t & 3;
            const float4* w4 = (const float4*)(W + d * 256 + h * 64);
            const float4* s4 = (const float4*)(att_s + h * 64);
            const float4* d4 = (const float4*)(att_d + h * 64);
            float vs = 0.f, vd = 0.f;
#pragma unroll
            for (int k = 0; k < 16; k++) {
                float4 w = w4[k], as = s4[k], ad = d4[k];
                vs = fmaf(w.x, as.x, fmaf(w.y, as.y, fmaf(w.z, as.z, fmaf(w.w, as.w, vs))));
                vd = fmaf(w.x, ad.x, fmaf(w.y, ad.y, fmaf(w.z, ad.z, fmaf(w.w, ad.w, vd))));
            }
            s_vs[h * 64 + d] = vs;
            s_vd[h * 64 + d] = vd;
        }
        // stage emb rows (coalesced float4)
#pragma unroll
        for (int r = 0; r < 4; r++) {
            int idx = (r * 256 + t) * 4;
            int i = idx >> 6, d = idx & 63;
            int row = min(n0 + i, N - 1);
            *(float4*)(s_e + i * 68 + d) = *(const float4*)(emb + (size_t)row * 64 + d);
        }
        __syncthreads();
        // logits: thread t -> (node = t>>2, h = t&3), float4 LDS reads
        const int node = t >> 2, h = t & 3;
        const float* er = s_e + node * 68;
        float as = 0.f, ad = 0.f;
#pragma unroll
        for (int g = 0; g < 16; g++) {
            float4 ev = *(const float4*)(er + 4 * g);
            float4 vs = *(const float4*)(s_vs + h * 64 + 4 * g);
            float4 vd = *(const float4*)(s_vd + h * 64 + 4 * g);
            as = fmaf(ev.x, vs.x, fmaf(ev.y, vs.y, fmaf(ev.z, vs.z, fmaf(ev.w, vs.w, as))));
            ad = fmaf(ev.x, vd.x, fmaf(ev.y, vd.y, fmaf(ev.z, vd.z, fmaf(ev.w, vd.w, ad))));
        }
        const int n = n0 + node;
        if (n < N) {                        // addresses = n0*4 + t: coalesced
            a_src[(size_t)n * 4 + h] = as;
            a_dst[(size_t)n * 4 + h] = ad;
            // emb16 pack: thread covers dims h*16..h*16+15 of its node (32 B)
            const float* ep = s_e + node * 68 + h * 16;
            uint4 u0, u1;
            u0.x = pack_half2(ep[0],  ep[1]);  u0.y = pack_half2(ep[2],  ep[3]);
            u0.z = pack_half2(ep[4],  ep[5]);  u0.w = pack_half2(ep[6],  ep[7]);
            u1.x = pack_half2(ep[8],  ep[9]);  u1.y = pack_half2(ep[10], ep[11]);
            u1.z = pack_half2(ep[12], ep[13]); u1.w = pack_half2(ep[14], ep[15]);
            unsigned* dst = embh + (size_t)n * 32 + h * 8;
            *(uint4*)dst = u0;
            *(uint4*)(dst + 4) = u1;
        }
        if (t < 64 && n0 + t < N) cnt[n0 + t] = 0;
    }
}

// ==================== K2: fill (XCD-partitioned by dst, standalone) ====================
__global__ __launch_bounds__(256) void fill_kernel(
        const int* __restrict__ gsrc, const int* __restrict__ gdst,
        int* __restrict__ cnt, int* __restrict__ adj, int E, int N) {
    const int t = threadIdx.x;
    const int part = blockIdx.x & (NPART - 1);
    const int slot = blockIdx.x >> 3;
    const int lo = (int)((long long)part * N / NPART);
    const int hi = (int)((long long)(part + 1) * N / NPART);
    const unsigned span = (unsigned)(hi - lo);
    const int quads = (E + 3) >> 2;
    const int stride = BPP * 256;

    for (int q = slot * 256 + t; q < quads; q += stride) {
        const int e0 = q * 4;
        v4i s4, d4;
        if (e0 + 3 < E) {
            d4 = __builtin_nontemporal_load((const v4i*)(gdst + e0));
            s4 = __builtin_nontemporal_load((const v4i*)(gsrc + e0));
        } else {
#pragma unroll
            for (int k = 0; k < 4; k++) {
                const int e = e0 + k;
                d4[k] = (e < E) ? gdst[e] : -1;   // -1 fails partition test
                s4[k] = (e < E) ? gsrc[e] : 0;
            }
        }
#pragma unroll
        for (int k = 0; k < 4; k++) {
            const int d = d4[k];
            if ((unsigned)(d - lo) < span) {
                const int pos = atomicAdd(&cnt[d], 1);
                if (pos < CAP) adj[(size_t)d * CAP + pos] = s4[k];
            }
        }
    }
}

// ==================== K3: aggregate (emb space) + outgemm, fused per 64-node tile ====
// Phase A: each wave aggregates 16 dsts (one at a time, same code as the old
//   aggregate kernel) and writes normalized zn16 rows into LDS (32 KB tile).
// Phase B: out = zn16 @ M2 + bvec straight from LDS; M2 (32 KB fp16) is read
//   from global — it's L1/L2-resident and broadcast-uniform per lane group.
// No zbuf global round-trip (saves ~51 MB traffic), one launch fewer.
__global__ __launch_bounds__(256) void agg_out_kernel(
        const int* __restrict__ cnt, const int* __restrict__ adj,
        const float* __restrict__ a_src, const float* __restrict__ a_dst,
        const unsigned* __restrict__ embh, const unsigned* __restrict__ M2u,
        const float* __restrict__ bvec, float* __restrict__ out, int N) {
    __shared__ unsigned s_z[8192];      // 64 nodes x 128 u32 (zn16)
    const int t = threadIdx.x;
    const int l = t & 63;
    const int wq = __builtin_amdgcn_readfirstlane(t >> 6);
    const int n0 = blockIdx.x * 64;
    const int hl = l >> 4;
    const int lh = l & 48;
    const int q = l & 15;
    const unsigned* el = embh + 2 * q;

    // ---------------- Phase A: aggregate 16 dsts per wave ----------------
    for (int it = 0; it < 16; ++it) {
        const int dd = n0 + wq * 16 + it;
        unsigned* zslot = s_z + (wq * 16 + it) * 128 + 2 * l;
        if (dd >= N) {
            *(uint2*)zslot = make_uint2(0u, 0u);
            continue;
        }
        const int d = __builtin_amdgcn_readfirstlane(dd);
        const int deg = min(__builtin_amdgcn_readfirstlane(cnt[d]), CAP);

        // adjacency into registers: lane e holds src of edge e
        int my_src = 0;
        if (l < deg) my_src = adj[(size_t)d * CAP + l];

        const float ad = a_dst[(size_t)d * 4 + hl];

        // precompute coefficients: lane l -> edge g*16+q, head hl
        float pv0, pv1, pv2, pv3;
        {
#define PRE_PV(G, PV) {                                                    \
            const int e_ = (G) * 16 + q;                                   \
            const int se_ = __shfl(my_src, e_, 64);                        \
            float pe_ = 0.f;                                               \
            if (e_ < deg)                                                  \
                pe_ = __expf(lrelu(a_src[(size_t)se_ * 4 + hl] + ad));     \
            (PV) = pe_; }
            PRE_PV(0, pv0); PRE_PV(1, pv1); PRE_PV(2, pv2); PRE_PV(3, pv3);
#undef PRE_PV
        }

        // self loop
        float den, zx, zy, zz, zw;
        {
            const float p = __expf(lrelu(a_src[(size_t)d * 4 + hl] + ad));
            const uint2 v = *(const uint2*)(el + (size_t)d * 32);
            const float2 f0 = __half22float2(*(const __half2*)&v.x);
            const float2 f1 = __half22float2(*(const __half2*)&v.y);
            den = p;
            zx = p * f0.x; zy = p * f0.y; zz = p * f1.x; zw = p * f1.y;
        }

#define AGG_EDGE(PG, I, J) {                                               \
        const int si_ = __builtin_amdgcn_readlane(my_src, (I));            \
        const float pe_ = __shfl((PG), lh + (J), 64);                      \
        const uint2 vv_ = *(const uint2*)(el + (size_t)si_ * 32);          \
        const float2 g0_ = __half22float2(*(const __half2*)&vv_.x);        \
        const float2 g1_ = __half22float2(*(const __half2*)&vv_.y);        \
        den += pe_;                                                        \
        zx = fmaf(pe_, g0_.x, zx); zy = fmaf(pe_, g0_.y, zy);              \
        zz = fmaf(pe_, g1_.x, zz); zw = fmaf(pe_, g1_.y, zw); }

#define AGG_GROUP(G, PG) {                                                 \
        const int base_ = (G) * 16;                                        \
        if (base_ < deg) {                                                 \
            const int mp_ = min(16, ((deg - base_) + 3) & ~3);             \
            _Pragma("unroll 1")                                            \
            for (int j = 0; j < mp_; j += 4) {                             \
                AGG_EDGE(PG, base_ + j + 0, j + 0);                        \
                AGG_EDGE(PG, base_ + j + 1, j + 1);                        \
                AGG_EDGE(PG, base_ + j + 2, j + 2);                        \
                AGG_EDGE(PG, base_ + j + 3, j + 3);                        \
            }                                                              \
        } }

        AGG_GROUP(0, pv0);
        AGG_GROUP(1, pv1);
        AGG_GROUP(2, pv2);
        AGG_GROUP(3, pv3);
#undef AGG_GROUP
#undef AGG_EDGE

        // normalize per head, write zn16 to LDS: fp16 idx 4l = hl*64+4q
        const float inv = 1.0f / (den + 1e-16f);
        uint2 u;
        u.x = pack_half2(zx * inv, zy * inv);
        u.y = pack_half2(zz * inv, zw * inv);
        *(uint2*)zslot = u;
    }
    __syncthreads();

    // ---------------- Phase B: out = zn16 @ M2 + bvec ----------------
    // lane l: k-quarter g=l>>4 (rotated kk to dodge bank conflicts),
    // out cols 4q..4q+3. Cross-group shfl reduce, lanes 0-15 write.
    const int g = l >> 4;
    const unsigned* zrow = s_z + (wq * 16) * 128 + g * 32;

    float4 acc[16];
#pragma unroll
    for (int i = 0; i < 16; i++) acc[i] = make_float4(0.f, 0.f, 0.f, 0.f);

#pragma unroll 2
    for (int i = 0; i < 32; i++) {
        const int kk = (i + 8 * g) & 31;        // rotation: groups hit distinct banks
        const int k = g * 64 + 2 * kk;
        const uint2 ma = *(const uint2*)(M2u + k * 32 + 2 * q);       // L1-hot 32 KB
        const uint2 mb = *(const uint2*)(M2u + (k + 1) * 32 + 2 * q);
        const float2 a0 = __half22float2(*(const __half2*)&ma.x);
        const float2 a1 = __half22float2(*(const __half2*)&ma.y);
        const float2 b0 = __half22float2(*(const __half2*)&mb.x);
        const float2 b1 = __half22float2(*(const __half2*)&mb.y);
#pragma unroll
        for (int n = 0; n < 16; n++) {
            const unsigned zp = zrow[n * 128 + kk];
            const float2 zf = __half22float2(*(const __half2*)&zp);
            acc[n].x = fmaf(zf.x, a0.x, acc[n].x);
            acc[n].y = fmaf(zf.x, a0.y, acc[n].y);
            acc[n].z = fmaf(zf.x, a1.x, acc[n].z);
            acc[n].w = fmaf(zf.x, a1.y, acc[n].w);
            acc[n].x = fmaf(zf.y, b0.x, acc[n].x);
            acc[n].y = fmaf(zf.y, b0.y, acc[n].y);
            acc[n].z = fmaf(zf.y, b1.x, acc[n].z);
            acc[n].w = fmaf(zf.y, b1.y, acc[n].w);
        }
    }

    const float4 bv = *(const float4*)(bvec + 4 * q);
#pragma unroll
    for (int n = 0; n < 16; n++) {
        float4 r = acc[n];
        r.x += __shfl_xor(r.x, 16, 64); r.y += __shfl_xor(r.y, 16, 64);
        r.z += __shfl_xor(r.z, 16, 64); r.w += __shfl_xor(r.w, 16, 64);
        r.x += __shfl_xor(r.x, 32, 64); r.y += __shfl_xor(r.y, 32, 64);
        r.z += __shfl_xor(r.z, 32, 64); r.w += __shfl_xor(r.w, 32, 64);
        const int nn = n0 + wq * 16 + n;
        if (l < 16 && nn < N) {
            float4 o;
            o.x = r.x + bv.x; o.y = r.y + bv.y; o.z = r.z + bv.z; o.w = r.w + bv.w;
            *(float4*)(out + (size_t)nn * 64 + 4 * q) = o;
        }
    }
}

extern "C" void kernel_launch(void* const* d_in, const int* in_sizes, int n_in,
                              void* d_out, int out_size, void* d_ws, size_t ws_size,
                              hipStream_t stream) {
    const float* emb   = (const float*)d_in[0];
    const int*   graph = (const int*)d_in[1];
    const float* W     = (const float*)d_in[2];
    const float* att_s = (const float*)d_in[3];
    const float* att_d = (const float*)d_in[4];
    const float* bias  = (const float*)d_in[5];
    const float* dw    = (const float*)d_in[6];
    const float* db    = (const float*)d_in[7];
    float* out = (float*)d_out;

    const int N = in_sizes[0] / DIM;
    const int E = in_sizes[1] / 2;
    const int* gsrc = graph;
    const int* gdst = graph + E;

    // workspace carve-up (~21 MB), all segments 16B-aligned
    int* adj       = (int*)d_ws;                         // N*CAP src indices
    unsigned* embh = (unsigned*)(adj + (size_t)N * CAP); // N*32 u32 (emb fp16)
    float* a_src   = (float*)(embh + (size_t)N * 32);    // N*4
    float* a_dst   = a_src + (size_t)N * 4;              // N*4
    __half* M2h    = (__half*)(a_dst + (size_t)N * 4);   // 256*64 fp16 (8192 u32)
    float* bvec    = (float*)((unsigned*)M2h + 8192);    // 64
    int*   cnt     = (int*)(bvec + 64);                  // N

    const int PB = (N + 63) / 64;                        // 64-node tiles
    const int FILLB = NPART * BPP;                       // 768 fill blocks

    hipLaunchKernelGGL(prep_kernel, dim3(65 + PB), dim3(256), 0, stream,
                       W, dw, att_s, att_d, bias, db, emb,
                       M2h, bvec, a_src, a_dst, embh, cnt, N);
    hipLaunchKernelGGL(fill_kernel, dim3(FILLB), dim3(256), 0, stream,
                       gsrc, gdst, cnt, adj, E, N);
    hipLaunchKernelGGL(agg_out_kernel, dim3(PB), dim3(256), 0, stream,
                       cnt, adj, a_src, a_dst, embh, (const unsigned*)M2h,
                       bvec, out, N);
}

// Round 7
// 216.524 us; speedup vs baseline: 1.2516x; 1.2516x over previous
//
#include <hip/hip_runtime.h>
#include <hip/hip_fp16.h>
#include <cfloat>
#include <cmath>

#define DIM 64
#define HEADS 4
#define NEG 0.2f
#define CAP 64          // bucket capacity; deg ~ Poisson(16), P(any node >64) ~ 1e-13
#define NPART 8         // dst partitions == XCD count; blockIdx&7 -> XCD (round-robin)
#define BPP 256         // fill blocks per partition (2048 total = 8 blocks/CU for TLP)

typedef int v4i __attribute__((ext_vector_type(4)));

__device__ __forceinline__ float lrelu(float a) { return a > 0.0f ? a : NEG * a; }

__device__ __forceinline__ unsigned pack_half2(float a, float b) {
    return (unsigned)__half_as_ushort(__float2half(a)) |
           ((unsigned)__half_as_ushort(__float2half(b)) << 16);
}

// ==================== K1: prep ====================
// b<64   : M2h[(h*64+d)][j] = fp16( sum_c W[d][64h+c]*dw[64h+c][j] )   (d = blockIdx)
// b==64  : bvec[j] = sum_k bias[k]*dw[k][j] + db[j]
// b>=65  : 64-node tile: logits a_src/a_dst = e.(W*att); emb16 row pack; zero cnt.
__global__ __launch_bounds__(256) void prep_kernel(
        const float* __restrict__ W, const float* __restrict__ dw,
        const float* __restrict__ att_s, const float* __restrict__ att_d,
        const float* __restrict__ bias, const float* __restrict__ db,
        const float* __restrict__ emb,
        __half* __restrict__ M2h, float* __restrict__ bvec,
        float* __restrict__ a_src, float* __restrict__ a_dst,
        unsigned* __restrict__ embh, int* __restrict__ cnt, int N) {
    const int b = blockIdx.x, t = threadIdx.x;
    if (b < 64) {
        __shared__ float s_W[256];
        s_W[t] = W[b * 256 + t];
        __syncthreads();
        const int h = t >> 6, j = t & 63;
        float s = 0.f;
        for (int c = 0; c < 64; c++)
            s = fmaf(s_W[h * 64 + c], dw[(h * 64 + c) * 64 + j], s);
        M2h[(size_t)(h * 64 + b) * 64 + j] = __float2half(s);
    } else if (b == 64) {
        __shared__ float s_p[256];
        const int j = t & 63, kq = t >> 6;
        float p = 0.f;
        for (int k = kq * 64; k < kq * 64 + 64; k++)
            p = fmaf(bias[k], dw[k * 64 + j], p);
        s_p[t] = p;
        __syncthreads();
        if (t < 64)
            bvec[t] = s_p[t] + s_p[64 + t] + s_p[128 + t] + s_p[192 + t] + db[t];
    } else {
        __shared__ float s_e[64 * 68];      // 64 emb rows, pad 68
        __shared__ float s_vs[256], s_vd[256];  // layout [h][d] = h*64+d
        const int n0 = (b - 65) * 64;
        // va: thread t -> (d = t>>2, h = t&3); vectorized float4 dots
        {
            const int d = t >> 2, h = t & 3;
            const float4* w4 = (const float4*)(W + d * 256 + h * 64);
            const float4* s4 = (const float4*)(att_s + h * 64);
            const float4* d4 = (const float4*)(att_d + h * 64);
            float vs = 0.f, vd = 0.f;
#pragma unroll
            for (int k = 0; k < 16; k++) {
                float4 w = w4[k], as = s4[k], ad = d4[k];
                vs = fmaf(w.x, as.x, fmaf(w.y, as.y, fmaf(w.z, as.z, fmaf(w.w, as.w, vs))));
                vd = fmaf(w.x, ad.x, fmaf(w.y, ad.y, fmaf(w.z, ad.z, fmaf(w.w, ad.w, vd))));
            }
            s_vs[h * 64 + d] = vs;
            s_vd[h * 64 + d] = vd;
        }
        // stage emb rows (coalesced float4)
#pragma unroll
        for (int r = 0; r < 4; r++) {
            int idx = (r * 256 + t) * 4;
            int i = idx >> 6, d = idx & 63;
            int row = min(n0 + i, N - 1);
            *(float4*)(s_e + i * 68 + d) = *(const float4*)(emb + (size_t)row * 64 + d);
        }
        __syncthreads();
        // logits: thread t -> (node = t>>2, h = t&3), float4 LDS reads
        const int node = t >> 2, h = t & 3;
        const float* er = s_e + node * 68;
        float as = 0.f, ad = 0.f;
#pragma unroll
        for (int g = 0; g < 16; g++) {
            float4 ev = *(const float4*)(er + 4 * g);
            float4 vs = *(const float4*)(s_vs + h * 64 + 4 * g);
            float4 vd = *(const float4*)(s_vd + h * 64 + 4 * g);
            as = fmaf(ev.x, vs.x, fmaf(ev.y, vs.y, fmaf(ev.z, vs.z, fmaf(ev.w, vs.w, as))));
            ad = fmaf(ev.x, vd.x, fmaf(ev.y, vd.y, fmaf(ev.z, vd.z, fmaf(ev.w, vd.w, ad))));
        }
        const int n = n0 + node;
        if (n < N) {                        // addresses = n0*4 + t: coalesced
            a_src[(size_t)n * 4 + h] = as;
            a_dst[(size_t)n * 4 + h] = ad;
            // emb16 pack: thread covers dims h*16..h*16+15 of its node (32 B)
            const float* ep = s_e + node * 68 + h * 16;
            uint4 u0, u1;
            u0.x = pack_half2(ep[0],  ep[1]);  u0.y = pack_half2(ep[2],  ep[3]);
            u0.z = pack_half2(ep[4],  ep[5]);  u0.w = pack_half2(ep[6],  ep[7]);
            u1.x = pack_half2(ep[8],  ep[9]);  u1.y = pack_half2(ep[10], ep[11]);
            u1.z = pack_half2(ep[12], ep[13]); u1.w = pack_half2(ep[14], ep[15]);
            unsigned* dst = embh + (size_t)n * 32 + h * 8;
            *(uint4*)dst = u0;
            *(uint4*)(dst + 4) = u1;
        }
        if (t < 64 && n0 + t < N) cnt[n0 + t] = 0;
    }
}

// ==================== K2: fill (XCD-partitioned by dst, standalone) ====================
__global__ __launch_bounds__(256) void fill_kernel(
        const int* __restrict__ gsrc, const int* __restrict__ gdst,
        int* __restrict__ cnt, int* __restrict__ adj, int E, int N) {
    const int t = threadIdx.x;
    const int part = blockIdx.x & (NPART - 1);
    const int slot = blockIdx.x >> 3;
    const int lo = (int)((long long)part * N / NPART);
    const int hi = (int)((long long)(part + 1) * N / NPART);
    const unsigned span = (unsigned)(hi - lo);
    const int quads = (E + 3) >> 2;
    const int stride = BPP * 256;

    for (int q = slot * 256 + t; q < quads; q += stride) {
        const int e0 = q * 4;
        v4i s4, d4;
        if (e0 + 3 < E) {
            d4 = __builtin_nontemporal_load((const v4i*)(gdst + e0));
            s4 = __builtin_nontemporal_load((const v4i*)(gsrc + e0));
        } else {
#pragma unroll
            for (int k = 0; k < 4; k++) {
                const int e = e0 + k;
                d4[k] = (e < E) ? gdst[e] : -1;   // -1 fails partition test
                s4[k] = (e < E) ? gsrc[e] : 0;
            }
        }
#pragma unroll
        for (int k = 0; k < 4; k++) {
            const int d = d4[k];
            if ((unsigned)(d - lo) < span) {
                const int pos = atomicAdd(&cnt[d], 1);
                if (pos < CAP) adj[(size_t)d * CAP + pos] = s4[k];
            }
        }
    }
}

// ==================== K3: aggregate in EMB space — one wave per dst ====================
// Lane l: head hl=l>>4, emb dims 4q..4q+3 (q=l&15). Per edge: one 128 B emb16
// row gather (4 head-groups read the same line -> coalesced once), 4 fp32
// accumulators z. Normalized zn written fp16 (512 B/wave). No y buffer.
__global__ __launch_bounds__(256) void aggregate_kernel(
        const int* __restrict__ cnt, const int* __restrict__ adj,
        const float* __restrict__ a_src, const float* __restrict__ a_dst,
        const unsigned* __restrict__ embh, unsigned* __restrict__ zbuf, int N) {
    const int t = threadIdx.x;
    const int l = t & 63;
    const int dd = blockIdx.x * 4 + (t >> 6);
    if (dd >= N) return;
    const int d = __builtin_amdgcn_readfirstlane(dd);   // uniform within wave
    const int hl = l >> 4;
    const int lh = l & 48;
    const int q = l & 15;
    const int deg = min(__builtin_amdgcn_readfirstlane(cnt[d]), CAP);
    const unsigned* el = embh + 2 * q;

    // ---- adjacency into registers: lane e holds src of edge e ----
    int my_src = 0;
    if (l < deg) my_src = adj[(size_t)d * CAP + l];

    const float ad = a_dst[(size_t)d * 4 + hl];

    // ---- precompute coefficients: lane l -> edge g*16+q, head hl ----
    float pv0, pv1, pv2, pv3;
    {
#define PRE_PV(G, PV) {                                                    \
            const int e_ = (G) * 16 + q;                                   \
            const int se_ = __shfl(my_src, e_, 64);                        \
            float pe_ = 0.f;                                               \
            if (e_ < deg)                                                  \
                pe_ = __expf(lrelu(a_src[(size_t)se_ * 4 + hl] + ad));     \
            (PV) = pe_; }
        PRE_PV(0, pv0); PRE_PV(1, pv1); PRE_PV(2, pv2); PRE_PV(3, pv3);
#undef PRE_PV
    }

    // ---- self loop ----
    float den, zx, zy, zz, zw;
    {
        const float p = __expf(lrelu(a_src[(size_t)d * 4 + hl] + ad));
        const uint2 v = *(const uint2*)(el + (size_t)d * 32);
        const float2 f0 = __half22float2(*(const __half2*)&v.x);
        const float2 f1 = __half22float2(*(const __half2*)&v.y);
        den = p;
        zx = p * f0.x; zy = p * f0.y; zz = p * f1.x; zw = p * f1.y;
    }

#define AGG_EDGE(PG, I, J) {                                               \
        const int si_ = __builtin_amdgcn_readlane(my_src, (I));            \
        const float pe_ = __shfl((PG), lh + (J), 64);                      \
        const uint2 vv_ = *(const uint2*)(el + (size_t)si_ * 32);          \
        const float2 g0_ = __half22float2(*(const __half2*)&vv_.x);        \
        const float2 g1_ = __half22float2(*(const __half2*)&vv_.y);        \
        den += pe_;                                                        \
        zx = fmaf(pe_, g0_.x, zx); zy = fmaf(pe_, g0_.y, zy);              \
        zz = fmaf(pe_, g1_.x, zz); zw = fmaf(pe_, g1_.y, zw); }

    // unroll 2: 8 independent gathers in flight per wave (was 4 with unroll 1)
#define AGG_GROUP(G, PG) {                                                 \
        const int base_ = (G) * 16;                                        \
        if (base_ < deg) {                                                 \
            const int mp_ = min(16, ((deg - base_) + 3) & ~3);             \
            _Pragma("unroll 2")                                            \
            for (int j = 0; j < mp_; j += 4) {                             \
                AGG_EDGE(PG, base_ + j + 0, j + 0);                        \
                AGG_EDGE(PG, base_ + j + 1, j + 1);                        \
                AGG_EDGE(PG, base_ + j + 2, j + 2);                        \
                AGG_EDGE(PG, base_ + j + 3, j + 3);                        \
            }                                                              \
        } }

    AGG_GROUP(0, pv0);
    AGG_GROUP(1, pv1);
    AGG_GROUP(2, pv2);
    AGG_GROUP(3, pv3);
#undef AGG_GROUP
#undef AGG_EDGE

    // ---- normalize per head, write zn16: fp16 idx 4l = hl*64+4q -> u32 idx 2l ----
    const float inv = 1.0f / (den + 1e-16f);
    uint2 u;
    u.x = pack_half2(zx * inv, zy * inv);
    u.y = pack_half2(zz * inv, zw * inv);
    *(uint2*)(zbuf + (size_t)dd * 128 + 2 * l) = u;
}

// ==================== K4: outgemm — out = zn16 @ M2 + bvec ====================
// 64 nodes/block; zn tile (32 KB) + M2 fp16 (32 KB) staged in LDS. 4 waves x
// 16 nodes; lane l: k-quarter g=l>>4 (rotated kk to dodge bank conflicts),
// out cols 4q..4q+3. Cross-group shfl reduce, lanes 0-15 write.
__global__ __launch_bounds__(256) void outgemm_kernel(
        const unsigned* __restrict__ zbuf, const unsigned* __restrict__ M2u,
        const float* __restrict__ bvec, float* __restrict__ out, int N) {
    __shared__ unsigned s_m[8192];      // M2 fp16 [256][64] -> [k][32 u32]
    __shared__ unsigned s_z[8192];      // 64 nodes x 128 u32
    const int t = threadIdx.x;
    const int n0 = blockIdx.x * 64;

#pragma unroll
    for (int r = 0; r < 8; r++)
        *(uint4*)(s_m + (r * 256 + t) * 4) = *(const uint4*)(M2u + (r * 256 + t) * 4);
#pragma unroll
    for (int r = 0; r < 8; r++) {
        const int idx = r * 256 + t;            // uint4 index (2048 total)
        const int row = idx >> 5, c4 = (idx & 31) * 4;
        const int n = n0 + row;
        uint4 v = make_uint4(0u, 0u, 0u, 0u);
        if (n < N) v = *(const uint4*)(zbuf + (size_t)n * 128 + c4);
        *(uint4*)(s_z + row * 128 + c4) = v;
    }
    __syncthreads();

    const int l = t & 63;
    const int wq = t >> 6;
    const int g = l >> 4, q = l & 15;
    const unsigned* zrow = s_z + (wq * 16) * 128 + g * 32;

    float4 acc[16];
#pragma unroll
    for (int i = 0; i < 16; i++) acc[i] = make_float4(0.f, 0.f, 0.f, 0.f);

#pragma unroll 2
    for (int i = 0; i < 32; i++) {
        const int kk = (i + 8 * g) & 31;        // rotation: groups hit distinct banks
        const int k = g * 64 + 2 * kk;
        const uint2 ma = *(const uint2*)(s_m + k * 32 + 2 * q);
        const uint2 mb = *(const uint2*)(s_m + (k + 1) * 32 + 2 * q);
        const float2 a0 = __half22float2(*(const __half2*)&ma.x);
        const float2 a1 = __half22float2(*(const __half2*)&ma.y);
        const float2 b0 = __half22float2(*(const __half2*)&mb.x);
        const float2 b1 = __half22float2(*(const __half2*)&mb.y);
#pragma unroll
        for (int n = 0; n < 16; n++) {
            const unsigned zp = zrow[n * 128 + kk];
            const float2 zf = __half22float2(*(const __half2*)&zp);
            acc[n].x = fmaf(zf.x, a0.x, acc[n].x);
            acc[n].y = fmaf(zf.x, a0.y, acc[n].y);
            acc[n].z = fmaf(zf.x, a1.x, acc[n].z);
            acc[n].w = fmaf(zf.x, a1.y, acc[n].w);
            acc[n].x = fmaf(zf.y, b0.x, acc[n].x);
            acc[n].y = fmaf(zf.y, b0.y, acc[n].y);
            acc[n].z = fmaf(zf.y, b1.x, acc[n].z);
            acc[n].w = fmaf(zf.y, b1.y, acc[n].w);
        }
    }

    const float4 bv = *(const float4*)(bvec + 4 * q);
#pragma unroll
    for (int n = 0; n < 16; n++) {
        float4 r = acc[n];
        r.x += __shfl_xor(r.x, 16, 64); r.y += __shfl_xor(r.y, 16, 64);
        r.z += __shfl_xor(r.z, 16, 64); r.w += __shfl_xor(r.w, 16, 64);
        r.x += __shfl_xor(r.x, 32, 64); r.y += __shfl_xor(r.y, 32, 64);
        r.z += __shfl_xor(r.z, 32, 64); r.w += __shfl_xor(r.w, 32, 64);
        const int nn = n0 + wq * 16 + n;
        if (l < 16 && nn < N) {
            float4 o;
            o.x = r.x + bv.x; o.y = r.y + bv.y; o.z = r.z + bv.z; o.w = r.w + bv.w;
            *(float4*)(out + (size_t)nn * 64 + 4 * q) = o;
        }
    }
}

extern "C" void kernel_launch(void* const* d_in, const int* in_sizes, int n_in,
                              void* d_out, int out_size, void* d_ws, size_t ws_size,
                              hipStream_t stream) {
    const float* emb   = (const float*)d_in[0];
    const int*   graph = (const int*)d_in[1];
    const float* W     = (const float*)d_in[2];
    const float* att_s = (const float*)d_in[3];
    const float* att_d = (const float*)d_in[4];
    const float* bias  = (const float*)d_in[5];
    const float* dw    = (const float*)d_in[6];
    const float* db    = (const float*)d_in[7];
    float* out = (float*)d_out;

    const int N = in_sizes[0] / DIM;
    const int E = in_sizes[1] / 2;
    const int* gsrc = graph;
    const int* gdst = graph + E;

    // workspace carve-up (~47 MB), all segments 16B-aligned
    unsigned* zbuf = (unsigned*)d_ws;                    // N*128 u32 (zn16)
    int* adj       = (int*)(zbuf + (size_t)N * 128);     // N*CAP src indices
    unsigned* embh = (unsigned*)(adj + (size_t)N * CAP); // N*32 u32 (emb fp16)
    float* a_src   = (float*)(embh + (size_t)N * 32);    // N*4
    float* a_dst   = a_src + (size_t)N * 4;              // N*4
    __half* M2h    = (__half*)(a_dst + (size_t)N * 4);   // 256*64 fp16 (8192 u32)
    float* bvec    = (float*)((unsigned*)M2h + 8192);    // 64
    int*   cnt     = (int*)(bvec + 64);                  // N

    const int PB = (N + 63) / 64;                        // 64-node tiles
    const int FILLB = NPART * BPP;                       // 2048 fill blocks

    hipLaunchKernelGGL(prep_kernel, dim3(65 + PB), dim3(256), 0, stream,
                       W, dw, att_s, att_d, bias, db, emb,
                       M2h, bvec, a_src, a_dst, embh, cnt, N);
    hipLaunchKernelGGL(fill_kernel, dim3(FILLB), dim3(256), 0, stream,
                       gsrc, gdst, cnt, adj, E, N);
    hipLaunchKernelGGL(aggregate_kernel, dim3((N + 3) / 4), dim3(256), 0, stream,
                       cnt, adj, a_src, a_dst, embh, zbuf, N);
    hipLaunchKernelGGL(outgemm_kernel, dim3(PB), dim3(256), 0, stream,
                       zbuf, (const unsigned*)M2h, bvec, out, N);
}